// Round 5
// baseline (230.815 us; speedup 1.0000x reference)
//
#include <hip/hip_runtime.h>
#include <stdint.h>

#define BB 8
#define NN 2048
#define CC 64
#define KK 32
#define DK 16
#define RADIUSF 0.2f
#define EPSF 1e-8f
#define BN_EPSF 1e-5f

typedef unsigned long long u64;
typedef unsigned int u32;

// --- fp32 helpers matching the reference's arithmetic ---
// sum of squares: elementwise square (rounded) then sequential reduce — no FMA
__device__ __forceinline__ float refsq3(float a, float b, float c) {
  return __fadd_rn(__fadd_rn(__fmul_rn(a, a), __fmul_rn(b, b)), __fmul_rn(c, c));
}
// einsum dot: BLAS/Eigen/XLA style acc = fma(a_k, b_k, acc), k ascending
__device__ __forceinline__ float refdot3(float ax, float ay, float az,
                                         float bx, float by, float bz) {
  return __builtin_fmaf(az, bz, __builtin_fmaf(ay, by, __fmul_rn(ax, bx)));
}
__device__ __forceinline__ float refdist(float sx, float sy, float dt) {
  float d2 = __fsub_rn(__fadd_rn(sx, sy), __fmul_rn(2.0f, dt));
  d2 = fmaxf(d2, 0.0f);
  return d2 > 0.0f ? __fsqrt_rn(d2) : 0.0f;
}

// ---------------------------------------------------------------------------
// Kernel 0: pack coords + exact ref-rounded sq-norm into float4 (x,y,z,sn).
// ---------------------------------------------------------------------------
__global__ __launch_bounds__(256) void pack_kernel(const float* __restrict__ coords,
                                                   float4* __restrict__ P) {
  int t = blockIdx.x * 256 + threadIdx.x;   // 0..16383
  float x = coords[t * 3 + 0], y = coords[t * 3 + 1], z = coords[t * 3 + 2];
  P[t] = make_float4(x, y, z, refsq3(x, y, z));
}

// ---------------------------------------------------------------------------
// Kernel 1: G[b][n][c] = inv[c]*(W_f[c,:]·feats[b,:,n]) + shift[c]
// ---------------------------------------------------------------------------
__global__ __launch_bounds__(256) void gfeat_kernel(
    const float* __restrict__ feats, const float* __restrict__ conv_w,
    const float* __restrict__ gamma, const float* __restrict__ beta,
    const float* __restrict__ mean, const float* __restrict__ var,
    float* __restrict__ G) {
  __shared__ float wlds[64 * 65];
  for (int e = threadIdx.x; e < 4096; e += 256) {
    int c = e >> 6, cp = e & 63;
    wlds[c * 65 + cp] = conv_w[c * (CC + 3) + 3 + cp];
  }
  __syncthreads();
  int t = blockIdx.x * 256 + threadIdx.x;   // t = m*64 + c
  int c = t & 63;
  int m = t >> 6;                            // b*N + n
  int b = m >> 11;
  int n = m & (NN - 1);
  float inv = __fdiv_rn(gamma[c], __fsqrt_rn(__fadd_rn(var[c], BN_EPSF)));
  float shift = __fsub_rn(beta[c], __fmul_rn(mean[c], inv));
  const float* f = feats + (size_t)b * CC * NN + n;   // stride NN over c'
  float acc = 0.f;
#pragma unroll
  for (int cp = 0; cp < CC; ++cp) acc = fmaf(wlds[c * 65 + cp], f[(size_t)cp * NN], acc);
  G[t] = fmaf(inv, acc, shift);
}

// ---------------------------------------------------------------------------
// Kernel 2: exact KNN-SET via byte-radix select (order-free: downstream is
// permutation-invariant). One wave per query, 4 queries per block.
// du = f32 bits of ref-rounded sqrt distance (monotone u32 for d>=0).
// 4 passes over bytes 3..0: 256-bin LDS histogram (4 replicas, stride 257)
// -> exact 32nd-smallest value D and residual count r. Collect du<D via
// prefix-scan positions; r smallest-index ties du==D via static ballots
// (c ascending, lane ascending == index ascending — matches top_k tie-break,
// though order is irrelevant since only the set matters).
// ---------------------------------------------------------------------------
__global__ __launch_bounds__(256, 8) void knn_kernel(const float4* __restrict__ P,
                                                     int* __restrict__ idx_out) {
  __shared__ u32 hist[4 * 1028];            // per-wave 1028 u32 (4 reps × 257)
  const int tid = threadIdx.x;
  const int lane = tid & 63;
  const int wv = tid >> 6;
  const int pid = blockIdx.x * 4 + wv;      // b*N + i
  const int b = pid >> 11;
  const int i = pid & (NN - 1);
  const float4* Pb = P + ((size_t)b << 11);
  float4 q = Pb[i];
  u32* h = hist + wv * 1028;
  u32* hr = h + (lane & 3) * 257;           // this lane's replica

  u32 du[32];
  // distance phase, fenced in chunks of 4 to bound VGPR pressure
#pragma unroll
  for (int cc = 0; cc < 8; ++cc) {
#pragma unroll
    for (int u = 0; u < 4; ++u) {
      const int c = cc * 4 + u;
      int j = (c << 6) | lane;
      float4 p = Pb[j];
      float dt = refdot3(q.x, q.y, q.z, p.x, p.y, p.z);
      du[c] = __float_as_uint(refdist(q.w, p.w, dt));
    }
    __builtin_amdgcn_sched_barrier(0);
  }

  u32 prefix = 0;
  u32 k_need = KK;
#pragma unroll
  for (int ps = 0; ps < 4; ++ps) {
    const int sh = 24 - 8 * ps;
    // zero this wave's histogram
    for (int w = lane; w < 1028; w += 64) h[w] = 0;
    __syncthreads();
    // accumulate
#pragma unroll
    for (int c = 0; c < 32; ++c) {
      bool act = (ps == 0) || ((du[c] >> (sh + 8)) == prefix);
      if (act) atomicAdd(&hr[(du[c] >> sh) & 0xFF], 1u);
    }
    __syncthreads();
    // per-lane totals of its 4 bins (sum 4 replicas)
    int b0 = 4 * lane;
    u32 t0 = h[b0] + h[257 + b0] + h[514 + b0] + h[771 + b0];
    u32 t1 = h[b0 + 1] + h[257 + b0 + 1] + h[514 + b0 + 1] + h[771 + b0 + 1];
    u32 t2 = h[b0 + 2] + h[257 + b0 + 2] + h[514 + b0 + 2] + h[771 + b0 + 2];
    u32 t3 = h[b0 + 3] + h[257 + b0 + 3] + h[514 + b0 + 3] + h[771 + b0 + 3];
    u32 s0 = t0, s1 = s0 + t1, s2 = s1 + t2, s3 = s2 + t3;
    // exclusive wave scan of s3
    u32 v = s3;
#pragma unroll
    for (int s = 1; s < 64; s <<= 1) {
      u32 o = __shfl_up(v, s, 64);
      if (lane >= s) v += o;
    }
    u32 excl = v - s3;
    // crossing bin: smallest bin with cumulative >= k_need
    u32 pack = 0xFFFFFFFFu;
    if (excl + s3 >= k_need) {
      u32 Bc, below;
      if (excl + s0 >= k_need)      { Bc = b0;     below = excl; }
      else if (excl + s1 >= k_need) { Bc = b0 + 1; below = excl + s0; }
      else if (excl + s2 >= k_need) { Bc = b0 + 2; below = excl + s1; }
      else                          { Bc = b0 + 3; below = excl + s2; }
      pack = (Bc << 12) | below;
    }
#pragma unroll
    for (int s = 1; s < 64; s <<= 1) {
      u32 o = __shfl_xor(pack, s);
      pack = o < pack ? o : pack;
    }
    prefix = (prefix << 8) | ((pack >> 12) & 0xFF);
    k_need -= (pack & 0xFFF);
    __syncthreads();   // protect histogram before next pass's zeroing
  }

  const u32 D = prefix;       // exact 32nd-smallest dist bits
  const u32 r = k_need;       // how many to take among du == D (>= 1)

  // collect du < D at prefix-scanned positions (order arbitrary)
  u32 cntL = 0;
#pragma unroll
  for (int c = 0; c < 32; ++c) cntL += (du[c] < D) ? 1u : 0u;
  u32 v2 = cntL;
#pragma unroll
  for (int s = 1; s < 64; s <<= 1) {
    u32 o = __shfl_up(v2, s, 64);
    if (lane >= s) v2 += o;
  }
  u32 pos = v2 - cntL;
  int* op = idx_out + (size_t)pid * KK;
#pragma unroll
  for (int c = 0; c < 32; ++c) {
    if (du[c] < D) { op[pos] = (c << 6) | lane; ++pos; }
  }
  // ties at D: take r smallest indices (c ascending, lane ascending)
  u32 rem = r;
#pragma unroll
  for (int c = 0; c < 32; ++c) {
    if (rem != 0) {
      u64 mask = __ballot(du[c] == D);
      while (mask != 0 && rem != 0) {
        int lw = (int)__ffsll((unsigned long long)mask) - 1;
        if (lane == lw) op[KK - rem] = (c << 6) | lw;
        --rem;
        mask &= mask - 1;
      }
    }
  }
}

// ---------------------------------------------------------------------------
// Kernel 3: density weights. 8 points per 256-thread block, 32 lanes/point.
// ---------------------------------------------------------------------------
__global__ __launch_bounds__(256) void density_kernel(const float* __restrict__ coords,
                                                      const int* __restrict__ idxb,
                                                      float* __restrict__ wbuf) {
  const int k = threadIdx.x & 31;
  const int sub = threadIdx.x >> 5;            // 0..7
  const int pid = blockIdx.x * 8 + sub;        // b*N + i
  const int b = pid >> 11;
  const float* cb = coords + (size_t)b * NN * 3;
  int j = idxb[(size_t)pid * KK + k];
  float nx = cb[j * 3 + 0], ny = cb[j * 3 + 1], nz = cb[j * 3 + 2];
  float sme = refsq3(nx, ny, nz);

  float d[32];
#pragma unroll
  for (int t = 0; t < 32; ++t) {
    float ox = __shfl(nx, t, 32);
    float oy = __shfl(ny, t, 32);
    float oz = __shfl(nz, t, 32);
    float so = refsq3(ox, oy, oz);
    float dt = refdot3(nx, ny, nz, ox, oy, oz);
    float dd = refdist(sme, so, dt);
    d[t] = (t == k) ? INFINITY : dd;   // eye mask
  }

  // sort 32 f32 ascending (values only; need the 16th smallest VALUE)
#pragma unroll
  for (int p = 1; p < 32; p <<= 1) {
#pragma unroll
    for (int kk = p; kk >= 1; kk >>= 1) {
#pragma unroll
      for (int jj = (kk & (p - 1)); jj + kk < 32; jj += 2 * kk) {
#pragma unroll
        for (int t = 0; t < kk; ++t) {
          if ((t + jj) / (2 * p) == (t + jj + kk) / (2 * p)) {
            float a = d[t + jj], b2 = d[t + jj + kk];
            float lo = fminf(a, b2);
            float hi = fmaxf(a, b2);
            d[t + jj] = lo;
            d[t + jj + kk] = hi;
          }
        }
      }
    }
  }

  float kth = d[DK - 1];
  float r1 = fmaxf(kth, EPSF);
  float raw = __fmul_rn(__fmul_rn(r1, r1), r1);
  float s = raw;
#pragma unroll
  for (int t = 1; t < 32; t <<= 1) s += __shfl_xor(s, t, 32);
  wbuf[(size_t)pid * KK + k] = raw / fmaxf(s, EPSF);
}

// ---------------------------------------------------------------------------
// Kernel 4: aggregation. One wave/point, lane = channel.
// ---------------------------------------------------------------------------
__global__ __launch_bounds__(256) void agg_kernel(
    const float* __restrict__ coords, const float* __restrict__ conv_w,
    const float* __restrict__ gamma, const float* __restrict__ var,
    const float* __restrict__ G, const int* __restrict__ idxb,
    const float* __restrict__ wbuf, float* __restrict__ out) {
  const int lane = threadIdx.x & 63;
  const int wv = threadIdx.x >> 6;
  const int pid = blockIdx.x * 4 + wv;   // b*N + i
  const int b = pid >> 11;
  const int i = pid & (NN - 1);
  const float* cb = coords + (size_t)b * NN * 3;

  float inv = __fdiv_rn(gamma[lane], __fsqrt_rn(__fadd_rn(var[lane], BN_EPSF)));
  float w0 = conv_w[lane * (CC + 3) + 0] * inv;
  float w1 = conv_w[lane * (CC + 3) + 1] * inv;
  float w2 = conv_w[lane * (CC + 3) + 2] * inv;

  float cx = cb[i * 3 + 0], cy = cb[i * 3 + 1], cz = cb[i * 3 + 2];
  float rx = 0.f, ry = 0.f, rz = 0.f, wk = 0.f;
  int jk = 0;
  if (lane < 32) {
    jk = idxb[(size_t)pid * KK + lane];
    rx = __fdiv_rn(__fsub_rn(cb[jk * 3 + 0], cx), RADIUSF);
    ry = __fdiv_rn(__fsub_rn(cb[jk * 3 + 1], cy), RADIUSF);
    rz = __fdiv_rn(__fsub_rn(cb[jk * 3 + 2], cz), RADIUSF);
    wk = wbuf[(size_t)pid * KK + lane];
  }

  float acc = 0.f;
#pragma unroll
  for (int k = 0; k < KK; ++k) {
    int j = __shfl(jk, k);
    float sx = __shfl(rx, k);
    float sy = __shfl(ry, k);
    float sz = __shfl(rz, k);
    float sw = __shfl(wk, k);
    float g = G[((size_t)(b * NN + j)) * 64 + lane];
    float y = fmaf(w2, sz, fmaf(w1, sy, fmaf(w0, sx, g)));
    y = fmaxf(y, 0.f);
    acc = fmaf(sw, y, acc);
  }
  out[((size_t)(b * 64 + lane)) * NN + i] = acc;
}

// ---------------------------------------------------------------------------
extern "C" void kernel_launch(void* const* d_in, const int* in_sizes, int n_in,
                              void* d_out, int out_size, void* d_ws, size_t ws_size,
                              hipStream_t stream) {
  const float* coords = (const float*)d_in[0];
  const float* feats  = (const float*)d_in[1];
  const float* conv_w = (const float*)d_in[2];
  const float* gamma  = (const float*)d_in[3];
  const float* beta   = (const float*)d_in[4];
  const float* mean   = (const float*)d_in[5];
  const float* var    = (const float*)d_in[6];
  float* out = (float*)d_out;

  int*   idxb = (int*)d_ws;                                          // 2 MB
  float* wbuf = (float*)((char*)d_ws + (size_t)2 * 1024 * 1024);     // 2 MB
  float* G    = (float*)((char*)d_ws + (size_t)4 * 1024 * 1024);     // 4 MB
  // P aliases the G region: knn consumes P before gfeat overwrites G.
  float4* P   = (float4*)G;                                          // 256 KB

  const int NPTS = BB * NN;   // 16384

  pack_kernel<<<NPTS / 256, 256, 0, stream>>>(coords, P);
  knn_kernel<<<NPTS / 4, 256, 0, stream>>>(P, idxb);
  gfeat_kernel<<<(NPTS * CC) / 256, 256, 0, stream>>>(feats, conv_w, gamma, beta,
                                                      mean, var, G);
  density_kernel<<<NPTS / 8, 256, 0, stream>>>(coords, idxb, wbuf);
  agg_kernel<<<NPTS / 4, 256, 0, stream>>>(coords, conv_w, gamma, var, G, idxb,
                                           wbuf, out);
}

// Round 6
// 162.542 us; speedup vs baseline: 1.4200x; 1.4200x over previous
//
#include <hip/hip_runtime.h>
#include <stdint.h>

#define BB 8
#define NN 2048
#define CC 64
#define KK 32
#define DK 16
#define RADIUSF 0.2f
#define EPSF 1e-8f
#define BN_EPSF 1e-5f

typedef unsigned long long u64;
typedef unsigned int u32;

// --- fp32 helpers matching the reference's arithmetic ---
// sum of squares: elementwise square (rounded) then sequential reduce — no FMA
__device__ __forceinline__ float refsq3(float a, float b, float c) {
  return __fadd_rn(__fadd_rn(__fmul_rn(a, a), __fmul_rn(b, b)), __fmul_rn(c, c));
}
// einsum dot: BLAS/Eigen/XLA style acc = fma(a_k, b_k, acc), k ascending
__device__ __forceinline__ float refdot3(float ax, float ay, float az,
                                         float bx, float by, float bz) {
  return __builtin_fmaf(az, bz, __builtin_fmaf(ay, by, __fmul_rn(ax, bx)));
}
__device__ __forceinline__ float refdist(float sx, float sy, float dt) {
  float d2 = __fsub_rn(__fadd_rn(sx, sy), __fmul_rn(2.0f, dt));
  d2 = fmaxf(d2, 0.0f);
  return d2 > 0.0f ? __fsqrt_rn(d2) : 0.0f;
}

// ---------------------------------------------------------------------------
// Kernel 0: pack coords + exact ref-rounded sq-norm into float4 (x,y,z,sn).
// ---------------------------------------------------------------------------
__global__ __launch_bounds__(256) void pack_kernel(const float* __restrict__ coords,
                                                   float4* __restrict__ P) {
  int t = blockIdx.x * 256 + threadIdx.x;   // 0..16383
  float x = coords[t * 3 + 0], y = coords[t * 3 + 1], z = coords[t * 3 + 2];
  P[t] = make_float4(x, y, z, refsq3(x, y, z));
}

// ---------------------------------------------------------------------------
// Kernel 1: G[b][n][c] = inv[c]*(W_f[c,:]·feats[b,:,n]) + shift[c]
// ---------------------------------------------------------------------------
__global__ __launch_bounds__(256) void gfeat_kernel(
    const float* __restrict__ feats, const float* __restrict__ conv_w,
    const float* __restrict__ gamma, const float* __restrict__ beta,
    const float* __restrict__ mean, const float* __restrict__ var,
    float* __restrict__ G) {
  __shared__ float wlds[64 * 65];
  for (int e = threadIdx.x; e < 4096; e += 256) {
    int c = e >> 6, cp = e & 63;
    wlds[c * 65 + cp] = conv_w[c * (CC + 3) + 3 + cp];
  }
  __syncthreads();
  int t = blockIdx.x * 256 + threadIdx.x;   // t = m*64 + c
  int c = t & 63;
  int m = t >> 6;                            // b*N + n
  int b = m >> 11;
  int n = m & (NN - 1);
  float inv = __fdiv_rn(gamma[c], __fsqrt_rn(__fadd_rn(var[c], BN_EPSF)));
  float shift = __fsub_rn(beta[c], __fmul_rn(mean[c], inv));
  const float* f = feats + (size_t)b * CC * NN + n;   // stride NN over c'
  float acc = 0.f;
#pragma unroll
  for (int cp = 0; cp < CC; ++cp) acc = fmaf(wlds[c * 65 + cp], f[(size_t)cp * NN], acc);
  G[t] = fmaf(inv, acc, shift);
}

// ---------------------------------------------------------------------------
// Kernel 2: exact KNN-SET via byte-radix select (order-free: downstream is
// permutation-invariant). One wave per query, 4 queries per block.
// du = f32 bits of ref-rounded sqrt distance (monotone u32 for d>=0).
// 4 passes over bytes 3..0: 256-bin LDS histogram (4 replicas, stride 257)
// -> exact 32nd-smallest value D and residual count r. Collect du<D via
// prefix-scan positions; r smallest-index ties du==D via static ballots.
// launch_bounds (256,4): 128-VGPR cap keeps du[32] IN REGISTERS (the (256,8)
// variant spilled to scratch: VGPR=32, FETCH 200MB, 179us — rule G6).
// ---------------------------------------------------------------------------
__global__ __launch_bounds__(256, 4) void knn_kernel(const float4* __restrict__ P,
                                                     int* __restrict__ idx_out) {
  __shared__ u32 hist[4 * 1028];            // per-wave 1028 u32 (4 reps × 257)
  const int tid = threadIdx.x;
  const int lane = tid & 63;
  const int wv = tid >> 6;
  const int pid = blockIdx.x * 4 + wv;      // b*N + i
  const int b = pid >> 11;
  const int i = pid & (NN - 1);
  const float4* Pb = P + ((size_t)b << 11);
  float4 q = Pb[i];
  u32* h = hist + wv * 1028;
  u32* hr = h + (lane & 3) * 257;           // this lane's replica

  u32 du[32];
#pragma unroll
  for (int c = 0; c < 32; ++c) {
    int j = (c << 6) | lane;
    float4 p = Pb[j];
    float dt = refdot3(q.x, q.y, q.z, p.x, p.y, p.z);
    du[c] = __float_as_uint(refdist(q.w, p.w, dt));
  }

  u32 prefix = 0;
  u32 k_need = KK;
#pragma unroll
  for (int ps = 0; ps < 4; ++ps) {
    const int sh = 24 - 8 * ps;
    // zero this wave's histogram
    for (int w = lane; w < 1028; w += 64) h[w] = 0;
    __syncthreads();
    // accumulate
#pragma unroll
    for (int c = 0; c < 32; ++c) {
      bool act = (ps == 0) || ((du[c] >> (sh + 8)) == prefix);
      if (act) atomicAdd(&hr[(du[c] >> sh) & 0xFF], 1u);
    }
    __syncthreads();
    // per-lane totals of its 4 bins (sum 4 replicas)
    int b0 = 4 * lane;
    u32 t0 = h[b0] + h[257 + b0] + h[514 + b0] + h[771 + b0];
    u32 t1 = h[b0 + 1] + h[257 + b0 + 1] + h[514 + b0 + 1] + h[771 + b0 + 1];
    u32 t2 = h[b0 + 2] + h[257 + b0 + 2] + h[514 + b0 + 2] + h[771 + b0 + 2];
    u32 t3 = h[b0 + 3] + h[257 + b0 + 3] + h[514 + b0 + 3] + h[771 + b0 + 3];
    u32 s0 = t0, s1 = s0 + t1, s2 = s1 + t2, s3 = s2 + t3;
    // exclusive wave scan of s3
    u32 v = s3;
#pragma unroll
    for (int s = 1; s < 64; s <<= 1) {
      u32 o = __shfl_up(v, s, 64);
      if (lane >= s) v += o;
    }
    u32 excl = v - s3;
    // crossing bin: smallest bin with cumulative >= k_need
    u32 pack = 0xFFFFFFFFu;
    if (excl + s3 >= k_need) {
      u32 Bc, below;
      if (excl + s0 >= k_need)      { Bc = b0;     below = excl; }
      else if (excl + s1 >= k_need) { Bc = b0 + 1; below = excl + s0; }
      else if (excl + s2 >= k_need) { Bc = b0 + 2; below = excl + s1; }
      else                          { Bc = b0 + 3; below = excl + s2; }
      pack = (Bc << 12) | below;
    }
#pragma unroll
    for (int s = 1; s < 64; s <<= 1) {
      u32 o = __shfl_xor(pack, s);
      pack = o < pack ? o : pack;
    }
    prefix = (prefix << 8) | ((pack >> 12) & 0xFF);
    k_need -= (pack & 0xFFF);
    __syncthreads();   // protect histogram before next pass's zeroing
  }

  const u32 D = prefix;       // exact 32nd-smallest dist bits
  const u32 r = k_need;       // how many to take among du == D (>= 1)

  // collect du < D at prefix-scanned positions (order arbitrary)
  u32 cntL = 0;
#pragma unroll
  for (int c = 0; c < 32; ++c) cntL += (du[c] < D) ? 1u : 0u;
  u32 v2 = cntL;
#pragma unroll
  for (int s = 1; s < 64; s <<= 1) {
    u32 o = __shfl_up(v2, s, 64);
    if (lane >= s) v2 += o;
  }
  u32 pos = v2 - cntL;
  int* op = idx_out + (size_t)pid * KK;
#pragma unroll
  for (int c = 0; c < 32; ++c) {
    if (du[c] < D) { op[pos] = (c << 6) | lane; ++pos; }
  }
  // ties at D: take r smallest indices (c ascending, lane ascending)
  u32 rem = r;
#pragma unroll
  for (int c = 0; c < 32; ++c) {
    if (rem != 0) {
      u64 mask = __ballot(du[c] == D);
      while (mask != 0 && rem != 0) {
        int lw = (int)__ffsll((unsigned long long)mask) - 1;
        if (lane == lw) op[KK - rem] = (c << 6) | lw;
        --rem;
        mask &= mask - 1;
      }
    }
  }
}

// ---------------------------------------------------------------------------
// Kernel 3: density weights. 8 points per 256-thread block, 32 lanes/point.
// ---------------------------------------------------------------------------
__global__ __launch_bounds__(256) void density_kernel(const float* __restrict__ coords,
                                                      const int* __restrict__ idxb,
                                                      float* __restrict__ wbuf) {
  const int k = threadIdx.x & 31;
  const int sub = threadIdx.x >> 5;            // 0..7
  const int pid = blockIdx.x * 8 + sub;        // b*N + i
  const int b = pid >> 11;
  const float* cb = coords + (size_t)b * NN * 3;
  int j = idxb[(size_t)pid * KK + k];
  float nx = cb[j * 3 + 0], ny = cb[j * 3 + 1], nz = cb[j * 3 + 2];
  float sme = refsq3(nx, ny, nz);

  float d[32];
#pragma unroll
  for (int t = 0; t < 32; ++t) {
    float ox = __shfl(nx, t, 32);
    float oy = __shfl(ny, t, 32);
    float oz = __shfl(nz, t, 32);
    float so = refsq3(ox, oy, oz);
    float dt = refdot3(nx, ny, nz, ox, oy, oz);
    float dd = refdist(sme, so, dt);
    d[t] = (t == k) ? INFINITY : dd;   // eye mask
  }

  // sort 32 f32 ascending (values only; need the 16th smallest VALUE)
#pragma unroll
  for (int p = 1; p < 32; p <<= 1) {
#pragma unroll
    for (int kk = p; kk >= 1; kk >>= 1) {
#pragma unroll
      for (int jj = (kk & (p - 1)); jj + kk < 32; jj += 2 * kk) {
#pragma unroll
        for (int t = 0; t < kk; ++t) {
          if ((t + jj) / (2 * p) == (t + jj + kk) / (2 * p)) {
            float a = d[t + jj], b2 = d[t + jj + kk];
            float lo = fminf(a, b2);
            float hi = fmaxf(a, b2);
            d[t + jj] = lo;
            d[t + jj + kk] = hi;
          }
        }
      }
    }
  }

  float kth = d[DK - 1];
  float r1 = fmaxf(kth, EPSF);
  float raw = __fmul_rn(__fmul_rn(r1, r1), r1);
  float s = raw;
#pragma unroll
  for (int t = 1; t < 32; t <<= 1) s += __shfl_xor(s, t, 32);
  wbuf[(size_t)pid * KK + k] = raw / fmaxf(s, EPSF);
}

// ---------------------------------------------------------------------------
// Kernel 4: aggregation. One wave/point, lane = channel.
// ---------------------------------------------------------------------------
__global__ __launch_bounds__(256) void agg_kernel(
    const float* __restrict__ coords, const float* __restrict__ conv_w,
    const float* __restrict__ gamma, const float* __restrict__ var,
    const float* __restrict__ G, const int* __restrict__ idxb,
    const float* __restrict__ wbuf, float* __restrict__ out) {
  const int lane = threadIdx.x & 63;
  const int wv = threadIdx.x >> 6;
  const int pid = blockIdx.x * 4 + wv;   // b*N + i
  const int b = pid >> 11;
  const int i = pid & (NN - 1);
  const float* cb = coords + (size_t)b * NN * 3;

  float inv = __fdiv_rn(gamma[lane], __fsqrt_rn(__fadd_rn(var[lane], BN_EPSF)));
  float w0 = conv_w[lane * (CC + 3) + 0] * inv;
  float w1 = conv_w[lane * (CC + 3) + 1] * inv;
  float w2 = conv_w[lane * (CC + 3) + 2] * inv;

  float cx = cb[i * 3 + 0], cy = cb[i * 3 + 1], cz = cb[i * 3 + 2];
  float rx = 0.f, ry = 0.f, rz = 0.f, wk = 0.f;
  int jk = 0;
  if (lane < 32) {
    jk = idxb[(size_t)pid * KK + lane];
    rx = __fdiv_rn(__fsub_rn(cb[jk * 3 + 0], cx), RADIUSF);
    ry = __fdiv_rn(__fsub_rn(cb[jk * 3 + 1], cy), RADIUSF);
    rz = __fdiv_rn(__fsub_rn(cb[jk * 3 + 2], cz), RADIUSF);
    wk = wbuf[(size_t)pid * KK + lane];
  }

  float acc = 0.f;
#pragma unroll
  for (int k = 0; k < KK; ++k) {
    int j = __shfl(jk, k);
    float sx = __shfl(rx, k);
    float sy = __shfl(ry, k);
    float sz = __shfl(rz, k);
    float sw = __shfl(wk, k);
    float g = G[((size_t)(b * NN + j)) * 64 + lane];
    float y = fmaf(w2, sz, fmaf(w1, sy, fmaf(w0, sx, g)));
    y = fmaxf(y, 0.f);
    acc = fmaf(sw, y, acc);
  }
  out[((size_t)(b * 64 + lane)) * NN + i] = acc;
}

// ---------------------------------------------------------------------------
extern "C" void kernel_launch(void* const* d_in, const int* in_sizes, int n_in,
                              void* d_out, int out_size, void* d_ws, size_t ws_size,
                              hipStream_t stream) {
  const float* coords = (const float*)d_in[0];
  const float* feats  = (const float*)d_in[1];
  const float* conv_w = (const float*)d_in[2];
  const float* gamma  = (const float*)d_in[3];
  const float* beta   = (const float*)d_in[4];
  const float* mean   = (const float*)d_in[5];
  const float* var    = (const float*)d_in[6];
  float* out = (float*)d_out;

  int*   idxb = (int*)d_ws;                                          // 2 MB
  float* wbuf = (float*)((char*)d_ws + (size_t)2 * 1024 * 1024);     // 2 MB
  float* G    = (float*)((char*)d_ws + (size_t)4 * 1024 * 1024);     // 4 MB
  // P aliases the G region: knn consumes P before gfeat overwrites G.
  float4* P   = (float4*)G;                                          // 256 KB

  const int NPTS = BB * NN;   // 16384

  pack_kernel<<<NPTS / 256, 256, 0, stream>>>(coords, P);
  knn_kernel<<<NPTS / 4, 256, 0, stream>>>(P, idxb);
  gfeat_kernel<<<(NPTS * CC) / 256, 256, 0, stream>>>(feats, conv_w, gamma, beta,
                                                      mean, var, G);
  density_kernel<<<NPTS / 8, 256, 0, stream>>>(coords, idxb, wbuf);
  agg_kernel<<<NPTS / 4, 256, 0, stream>>>(coords, conv_w, gamma, var, G, idxb,
                                           wbuf, out);
}